// Round 3
// baseline (2755.932 us; speedup 1.0000x reference)
//
#include <hip/hip_runtime.h>
#include <stdint.h>

#define B_    1024
#define P_    100
#define N_    101
#define EMB_  128
#define H_    8
#define DK_   16
#define CAT_  (EMB_ + 4)

__device__ __forceinline__ float b2f(uint16_t u) {
    union { uint32_t i; float f; } c; c.i = ((uint32_t)u) << 16; return c.f;
}
__device__ __forceinline__ uint16_t f2b(float f) {
    union { float f; uint32_t i; } c; c.f = f;
    uint32_t i = c.i;
    uint32_t r = (i + 0x7fffu + ((i >> 16) & 1u)) >> 16;  // RNE
    return (uint16_t)r;
}

__global__ __launch_bounds__(256, 2)
void vrp_kernel(const float* __restrict__ eln,
                const float* __restrict__ load_,
                const float* __restrict__ time_,
                const float* __restrict__ len_,
                const float* __restrict__ open_,
                const float* __restrict__ mask_,
                const float* __restrict__ enc_,
                const float* __restrict__ Wq,
                const float* __restrict__ Wk,
                const float* __restrict__ Wv,
                const float* __restrict__ Wc,
                const float* __restrict__ bc,
                float* __restrict__ out)
{
    const int b   = blockIdx.x;
    const int tid = threadIdx.x;
    const int wave = tid >> 6, lane = tid & 63;

    // K transposed [h][d][n] -> conflict-free reads in score stage.
    // V natural    [h][n][d] -> conflict-free reads in PV stage.
    __shared__ uint16_t sK[H_ * DK_ * N_];   // 25856 B
    __shared__ uint16_t sV[H_ * N_ * DK_];   // 25856 B
    __shared__ float sW[2 * H_ * N_];        // attn scores/weights [pp][h][n] 6464 B
    __shared__ float sCat[2 * CAT_];         // 1056 B
    __shared__ float sQ[2 * EMB_];           // 1024 B
    __shared__ float sO[2 * EMB_];           // 1024 B
    __shared__ float sM[2 * EMB_];           // 1024 B
    __shared__ float sS2[2 * N_];            // 808 B

    const float* encB = enc_ + (size_t)b * N_ * EMB_;

    // ---------- Phase 1: K = enc @ Wk, V = enc @ Wv ----------
    // thread j handles (node n, output pair o, o+1) for both K and V
    for (int j = tid; j < N_ * 64; j += 256) {
        int n  = j >> 6;
        int o  = (j & 63) << 1;
        float k0 = 0.f, k1 = 0.f, v0 = 0.f, v1 = 0.f;
        const float* er = encB + n * EMB_;
        for (int i = 0; i < EMB_; i += 4) {
            float4 e4 = *(const float4*)(er + i);
            #pragma unroll
            for (int t = 0; t < 4; ++t) {
                float e = (t == 0) ? e4.x : (t == 1) ? e4.y : (t == 2) ? e4.z : e4.w;
                float2 wk = *(const float2*)(Wk + (size_t)(i + t) * EMB_ + o);
                float2 wv = *(const float2*)(Wv + (size_t)(i + t) * EMB_ + o);
                k0 += e * wk.x; k1 += e * wk.y;
                v0 += e * wv.x; v1 += e * wv.y;
            }
        }
        int h = o >> 4, d = o & 15;
        sK[(size_t)o * N_ + n]       = f2b(k0);   // transposed: [o][n]
        sK[(size_t)(o + 1) * N_ + n] = f2b(k1);
        uint32_t vp = (uint32_t)f2b(v0) | ((uint32_t)f2b(v1) << 16);
        *(uint32_t*)&sV[((size_t)h * N_ + n) * DK_ + d] = vp;
    }
    __syncthreads();

    // ---------- Main loop: 2 queries (p) per iteration ----------
    for (int pb = 0; pb < P_; pb += 2) {
        // A: build cat = [eln(128), load, time, length, route_open]
        {
            int pp = tid >> 7, jj = tid & 127;
            int p = pb + pp;
            sCat[pp * CAT_ + jj] = eln[((size_t)b * P_ + p) * EMB_ + jj];
            if (jj < 4) {
                const float* s4 = (jj == 0) ? load_ : (jj == 1) ? time_
                                 : (jj == 2) ? len_ : open_;
                sCat[pp * CAT_ + EMB_ + jj] = s4[(size_t)b * P_ + p];
            }
        }
        __syncthreads();

        // B: q = cat @ Wq
        {
            int pp = tid >> 7, o = tid & 127;
            const float* c = sCat + pp * CAT_;
            float acc = 0.f;
            for (int i = 0; i < CAT_; ++i)
                acc += c[i] * Wq[(size_t)i * EMB_ + o];
            sQ[pp * EMB_ + o] = acc;
        }
        __syncthreads();

        // C: scores = q.k / 4 + mask
        for (int idx = tid; idx < 2 * H_ * N_; idx += 256) {
            int pp  = (idx >= H_ * N_) ? 1 : 0;
            int rem = idx - pp * H_ * N_;
            int h = rem / N_;
            int n = rem - h * N_;
            const float*    q  = sQ + pp * EMB_ + h * DK_;
            const uint16_t* kk = sK + (size_t)h * DK_ * N_ + n;
            float s = 0.f;
            #pragma unroll
            for (int d = 0; d < DK_; ++d)
                s += q[d] * b2f(kk[(size_t)d * N_]);
            int p = pb + pp;
            s = s * 0.25f + mask_[((size_t)b * P_ + p) * N_ + n];
            sW[idx] = s;
        }
        __syncthreads();

        // D: softmax over n for each (pp, h) — one wave per instance
        for (int u = wave; u < 16; u += 4) {
            float* row = sW + u * N_;
            float m = -3.0e38f;
            for (int n = lane; n < N_; n += 64) m = fmaxf(m, row[n]);
            #pragma unroll
            for (int off = 32; off; off >>= 1) m = fmaxf(m, __shfl_xor(m, off));
            float sum = 0.f;
            for (int n = lane; n < N_; n += 64) {
                float e = __expf(row[n] - m);
                row[n] = e;
                sum += e;
            }
            #pragma unroll
            for (int off = 32; off; off >>= 1) sum += __shfl_xor(sum, off);
            float inv = 1.0f / sum;
            for (int n = lane; n < N_; n += 64) row[n] *= inv;
        }
        __syncthreads();

        // E: out = weights @ V   (out_concat order o = h*16+d)
        {
            int pp = tid >> 7, o = tid & 127;
            int h = o >> 4, d = o & 15;
            const float*    w  = sW + ((size_t)pp * H_ + h) * N_;
            const uint16_t* vv = sV + (size_t)h * N_ * DK_ + d;
            float acc = 0.f;
            for (int n = 0; n < N_; ++n)
                acc += w[n] * b2f(vv[(size_t)n * DK_]);
            sO[pp * EMB_ + o] = acc;
        }
        __syncthreads();

        // F: mh = out @ Wc + bc
        {
            int pp = tid >> 7, e = tid & 127;
            const float* oc = sO + pp * EMB_;
            float acc = bc[e];
            for (int i = 0; i < EMB_; ++i)
                acc += oc[i] * Wc[(size_t)i * EMB_ + e];
            sM[pp * EMB_ + e] = acc;
        }
        __syncthreads();

        // G: score2 = 10*tanh(mh . enc / sqrt(128)) + mask ; 2 threads per (pp,n)
        {
            int g = tid >> 1, sub = tid & 1;
            for (int inst = g; inst < 2 * N_; inst += 128) {
                int pp = (inst >= N_) ? 1 : 0;
                int n  = inst - pp * N_;
                const float* mrow = sM + pp * EMB_ + sub * 64;
                const float* er   = encB + (size_t)n * EMB_ + sub * 64;
                float s = 0.f;
                #pragma unroll
                for (int i = 0; i < 64; i += 4) {
                    float4 e4 = *(const float4*)(er + i);
                    s += mrow[i]     * e4.x;
                    s += mrow[i + 1] * e4.y;
                    s += mrow[i + 2] * e4.z;
                    s += mrow[i + 3] * e4.w;
                }
                s += __shfl_xor(s, 1);
                if (sub == 0) {
                    int p = pb + pp;
                    float x = s * 0.08838834764831845f;          // 1/sqrt(128)
                    float t = 1.0f - 2.0f / (__expf(2.0f * x) + 1.0f);  // tanh, safe
                    sS2[pp * N_ + n] = 10.0f * t
                        + mask_[((size_t)b * P_ + p) * N_ + n];
                }
            }
        }
        __syncthreads();

        // H: final softmax over n, write f32 probs — wave 0 -> pp0, wave 1 -> pp1
        if (wave < 2) {
            int pp = wave;
            const float* row = sS2 + pp * N_;
            float m = -3.0e38f;
            for (int n = lane; n < N_; n += 64) m = fmaxf(m, row[n]);
            #pragma unroll
            for (int off = 32; off; off >>= 1) m = fmaxf(m, __shfl_xor(m, off));
            float sum = 0.f;
            for (int n = lane; n < N_; n += 64) sum += __expf(row[n] - m);
            #pragma unroll
            for (int off = 32; off; off >>= 1) sum += __shfl_xor(sum, off);
            float inv = 1.0f / sum;
            float* orow = out + ((size_t)b * P_ + pb + pp) * N_;
            for (int n = lane; n < N_; n += 64)
                orow[n] = __expf(row[n] - m) * inv;
        }
        __syncthreads();
    }
}

extern "C" void kernel_launch(void* const* d_in, const int* in_sizes, int n_in,
                              void* d_out, int out_size, void* d_ws, size_t ws_size,
                              hipStream_t stream) {
    const float* eln   = (const float*)d_in[0];
    const float* load_ = (const float*)d_in[1];
    const float* time_ = (const float*)d_in[2];
    const float* len_  = (const float*)d_in[3];
    const float* open_ = (const float*)d_in[4];
    const float* mask_ = (const float*)d_in[5];
    const float* enc_  = (const float*)d_in[6];
    const float* Wq    = (const float*)d_in[7];
    const float* Wk    = (const float*)d_in[8];
    const float* Wv    = (const float*)d_in[9];
    const float* Wc    = (const float*)d_in[10];
    const float* bc    = (const float*)d_in[11];
    float* out = (float*)d_out;

    vrp_kernel<<<dim3(B_), dim3(256), 0, stream>>>(
        eln, load_, time_, len_, open_, mask_, enc_, Wq, Wk, Wv, Wc, bc, out);
}

// Round 5
// 360.485 us; speedup vs baseline: 7.6451x; 7.6451x over previous
//
#include <hip/hip_runtime.h>
#include <stdint.h>

#define B_    1024
#define P_    100
#define N_    101
#define EMB_  128
#define H_    8
#define DK_   16

#define ROWS  112          // 7 m-tiles of 16 (covers P=100 / N=101)
#define KSTR  136          // LDS row stride in bf16 elems (272 B -> 2-way-free banks)

typedef uint16_t bf16;
typedef __attribute__((ext_vector_type(8))) short short8;
typedef __attribute__((ext_vector_type(4))) float float4v;

__device__ __forceinline__ float b2f(bf16 u) {
    union { uint32_t i; float f; } c; c.i = ((uint32_t)u) << 16; return c.f;
}
__device__ __forceinline__ bf16 f2b(float f) {
    union { float f; uint32_t i; } c; c.f = f;
    uint32_t r = (c.i + 0x7fffu + ((c.i >> 16) & 1u)) >> 16;   // RNE
    return (bf16)r;
}
__device__ __forceinline__ uint32_t pk2(float a, float b) {
    return (uint32_t)f2b(a) | ((uint32_t)f2b(b) << 16);
}

// stage f32 [nrows][128] row-major -> bf16 LDS [ROWS][KSTR], zero pad rows
__device__ __forceinline__ void stage_m(const float* __restrict__ src, int nrows,
                                        bf16* __restrict__ dst, int tid) {
    for (int i = tid; i < ROWS * 32; i += 512) {
        int r = i >> 5, c = (i & 31) << 2;
        uint32_t p0 = 0, p1 = 0;
        if (r < nrows) {
            float4 v = *(const float4*)(src + (size_t)r * EMB_ + c);
            p0 = pk2(v.x, v.y); p1 = pk2(v.z, v.w);
        }
        uint32_t* d = (uint32_t*)(dst + r * KSTR + c);
        d[0] = p0; d[1] = p1;
    }
}

// stage W^T chunk: W f32 [128+][128], outs [out0,out0+32) -> dst bf16 [32][KSTR]
__device__ __forceinline__ void stage_wT(const float* __restrict__ W, int out0,
                                         bf16* __restrict__ dst, int tid) {
    int k  = tid >> 2;           // 0..127
    int og = (tid & 3) << 3;     // 0,8,16,24
    const float* src = W + (size_t)k * EMB_ + out0 + og;
    float4 v0 = *(const float4*)(src);
    float4 v1 = *(const float4*)(src + 4);
    bf16* d = dst + k;
    d[(og + 0) * KSTR] = f2b(v0.x);
    d[(og + 1) * KSTR] = f2b(v0.y);
    d[(og + 2) * KSTR] = f2b(v0.z);
    d[(og + 3) * KSTR] = f2b(v0.w);
    d[(og + 4) * KSTR] = f2b(v1.x);
    d[(og + 5) * KSTR] = f2b(v1.y);
    d[(og + 6) * KSTR] = f2b(v1.z);
    d[(og + 7) * KSTR] = f2b(v1.w);
}

__global__ __launch_bounds__(512, 2)
void vrp_kernel(const float* __restrict__ eln,
                const float* __restrict__ load_,
                const float* __restrict__ time_,
                const float* __restrict__ len_,
                const float* __restrict__ open_,
                const float* __restrict__ mask_,
                const float* __restrict__ enc_,
                const float* __restrict__ Wq,
                const float* __restrict__ Wk,
                const float* __restrict__ Wv,
                const float* __restrict__ Wc,
                const float* __restrict__ bc,
                float* __restrict__ out)
{
    const int b    = blockIdx.x;
    const int tid  = threadIdx.x;
    const int wave = tid >> 6;
    const int lane = tid & 63;
    const int lr = lane & 15, lq = lane >> 4, lk = lq << 3;

    // Region overlays (bf16 elems): R1 sEnc/sCat/sP/sMhLo ; R2 sK/sWc/sEnc2 ;
    // R3 sVt ; R4 sQ/sMhHi ; R5 sWb-chunks/sOut.  Total 160,512 B static.
    __shared__ bf16 smem[78336];
    __shared__ float sS4[ROWS * 4];
    __shared__ float sWq4[4 * EMB_];
    bf16* const R1 = smem;
    bf16* const R2 = smem + 15232;
    bf16* const R3 = smem + 30464;
    bf16* const R4 = smem + 47872;
    bf16* const R5 = smem + 63104;

    const float* encB  = enc_  + (size_t)b * N_ * EMB_;
    const float* elnB  = eln   + (size_t)b * P_ * EMB_;
    const float* maskB = mask_ + (size_t)b * P_ * N_;
    float*       outB  = out   + (size_t)b * P_ * N_;

    // ---------------- Phase A: enc -> R1 bf16 ; zero sVt pad cols ----------
    stage_m(encB, N_, R1, tid);
    {   // zero sVt[d][112..127]  (PV kstep 3 reads n=96..127)
        int d = tid >> 2, c = 112 + ((tid & 3) << 2);
        uint32_t* z = (uint32_t*)(R3 + d * KSTR + c);
        z[0] = 0; z[1] = 0;
    }

    // ---------------- Phase B: K = enc@Wk -> R2 ; V^T -> R3 ----------------
    for (int wv = 0; wv < 2; ++wv) {
        const float* W = wv ? Wv : Wk;
        for (int out0 = 0; out0 < EMB_; out0 += 32) {
            __syncthreads();
            stage_wT(W, out0, R5, tid);
            __syncthreads();
            for (int job = wave; job < 14; job += 8) {
                int mt = job >> 1, nt = job & 1;
                float4v c = {0.f, 0.f, 0.f, 0.f};
                #pragma unroll
                for (int ks = 0; ks < 128; ks += 32) {
                    short8 a  = *(const short8*)(R1 + (mt * 16 + lr) * KSTR + ks + lk);
                    short8 bb = *(const short8*)(R5 + (nt * 16 + lr) * KSTR + ks + lk);
                    c = __builtin_amdgcn_mfma_f32_16x16x32_bf16(a, bb, c, 0, 0, 0);
                }
                int n0  = mt * 16 + (lq << 2);
                int col = out0 + nt * 16 + lr;
                if (!wv) {
                    #pragma unroll
                    for (int r = 0; r < 4; ++r)
                        R2[(n0 + r) * KSTR + col] = f2b(c[r]);
                } else {   // V^T: [d][n], 4 consecutive n -> one 8B write
                    uint32_t* d = (uint32_t*)(R3 + col * KSTR + n0);
                    d[0] = pk2(c[0], c[1]);
                    d[1] = pk2(c[2], c[3]);
                }
            }
        }
    }

    // ---------------- Phase C: cat -> R1 ; Q' = 0.25*(cat@Wq) -> R4 --------
    __syncthreads();
    stage_m(elnB, P_, R1, tid);
    if (tid < ROWS * 4) {
        int r = tid >> 2, j = tid & 3;
        float v = 0.f;
        if (r < P_) {
            const float* s4 = (j == 0) ? load_ : (j == 1) ? time_
                             : (j == 2) ? len_ : open_;
            v = s4[(size_t)b * P_ + r];
        }
        sS4[r * 4 + j] = v;
    }
    {
        int j = tid >> 7, c = tid & 127;
        sWq4[j * EMB_ + c] = Wq[(size_t)(EMB_ + j) * EMB_ + c];
    }
    for (int out0 = 0; out0 < EMB_; out0 += 32) {
        __syncthreads();
        stage_wT(Wq, out0, R5, tid);
        __syncthreads();
        for (int job = wave; job < 14; job += 8) {
            int mt = job >> 1, nt = job & 1;
            float4v c = {0.f, 0.f, 0.f, 0.f};
            #pragma unroll
            for (int ks = 0; ks < 128; ks += 32) {
                short8 a  = *(const short8*)(R1 + (mt * 16 + lr) * KSTR + ks + lk);
                short8 bb = *(const short8*)(R5 + (nt * 16 + lr) * KSTR + ks + lk);
                c = __builtin_amdgcn_mfma_f32_16x16x32_bf16(a, bb, c, 0, 0, 0);
            }
            int row0 = mt * 16 + (lq << 2);
            int col  = out0 + nt * 16 + lr;
            float w0 = sWq4[col], w1 = sWq4[EMB_ + col];
            float w2 = sWq4[2 * EMB_ + col], w3 = sWq4[3 * EMB_ + col];
            #pragma unroll
            for (int r = 0; r < 4; ++r) {
                const float* s4 = sS4 + (row0 + r) * 4;
                float acc = c[r] + s4[0] * w0 + s4[1] * w1 + s4[2] * w2 + s4[3] * w3;
                R4[(row0 + r) * KSTR + col] = f2b(acc * 0.25f);   // fold 1/sqrt(DK), exact
            }
        }
    }

    // ---------------- Phase D: attention (no barriers inside) --------------
    __syncthreads();
    float msk[7][4];
    if (wave < 7) {
        {   // zero sP pad cols 112..127 of my p-tile
            uint32_t* z = (uint32_t*)(R1 + (wave * 16 + lr) * KSTR + 112 + (lq << 2));
            z[0] = 0; z[1] = 0;
        }
        #pragma unroll
        for (int nt = 0; nt < 7; ++nt) {
            int n = nt * 16 + lr;
            #pragma unroll
            for (int r = 0; r < 4; ++r) {
                int p = wave * 16 + (lq << 2) + r;
                float v;
                if (n >= N_) v = -3.0e38f;
                else if (p < P_) v = maskB[(size_t)p * N_ + n];
                else v = 0.f;
                msk[nt][r] = v;
            }
        }
        for (int h = 0; h < H_; ++h) {
            int k0 = (h >> 1) << 5;                 // 32-wide k-window
            float sc[7][4];
            short8 a = *(const short8*)(R4 + (wave * 16 + lr) * KSTR + k0 + lk);
            #pragma unroll
            for (int nt = 0; nt < 7; ++nt) {
                short8 bb = *(const short8*)(R2 + (nt * 16 + lr) * KSTR + k0 + lk);
                if ((lq >> 1) != (h & 1)) bb = (short8){0,0,0,0,0,0,0,0};  // kill other head's half
                float4v cc = {0.f, 0.f, 0.f, 0.f};
                cc = __builtin_amdgcn_mfma_f32_16x16x32_bf16(a, bb, cc, 0, 0, 0);
                #pragma unroll
                for (int r = 0; r < 4; ++r) sc[nt][r] = cc[r] + msk[nt][r];
            }
            #pragma unroll
            for (int r = 0; r < 4; ++r) {           // in-register row softmax
                float m = sc[0][r];
                #pragma unroll
                for (int nt = 1; nt < 7; ++nt) m = fmaxf(m, sc[nt][r]);
                #pragma unroll
                for (int d = 1; d < 16; d <<= 1) m = fmaxf(m, __shfl_xor(m, d));
                float su = 0.f;
                #pragma unroll
                for (int nt = 0; nt < 7; ++nt) {
                    float e = __expf(sc[nt][r] - m); sc[nt][r] = e; su += e;
                }
                #pragma unroll
                for (int d = 1; d < 16; d <<= 1) su += __shfl_xor(su, d);
                float inv = 1.0f / su;
                #pragma unroll
                for (int nt = 0; nt < 7; ++nt)      // P -> LDS in A-layout
                    R1[(wave * 16 + (lq << 2) + r) * KSTR + nt * 16 + lr] =
                        f2b(sc[nt][r] * inv);
            }
            float4v o = {0.f, 0.f, 0.f, 0.f};       // PV
            #pragma unroll
            for (int ks = 0; ks < 128; ks += 32) {
                short8 a2 = *(const short8*)(R1 + (wave * 16 + lr) * KSTR + ks + lk);
                short8 b2 = *(const short8*)(R3 + (h * 16 + lr) * KSTR + ks + lk);
                o = __builtin_amdgcn_mfma_f32_16x16x32_bf16(a2, b2, o, 0, 0, 0);
            }
            #pragma unroll
            for (int r = 0; r < 4; ++r)
                R5[(wave * 16 + (lq << 2) + r) * KSTR + h * 16 + lr] = f2b(o[r]);
        }
    }

    // ---------------- Phase E: mh = out@Wc + bc -> hi(R4) + lo(R1) ---------
    for (int out0 = 0; out0 < EMB_; out0 += 32) {
        __syncthreads();
        stage_wT(Wc, out0, R2, tid);
        __syncthreads();
        for (int job = wave; job < 14; job += 8) {
            int mt = job >> 1, nt = job & 1;
            float4v c = {0.f, 0.f, 0.f, 0.f};
            #pragma unroll
            for (int ks = 0; ks < 128; ks += 32) {
                short8 a  = *(const short8*)(R5 + (mt * 16 + lr) * KSTR + ks + lk);
                short8 bb = *(const short8*)(R2 + (nt * 16 + lr) * KSTR + ks + lk);
                c = __builtin_amdgcn_mfma_f32_16x16x32_bf16(a, bb, c, 0, 0, 0);
            }
            int row0 = mt * 16 + (lq << 2);
            int col  = out0 + nt * 16 + lr;
            float bcv = bc[col];
            #pragma unroll
            for (int r = 0; r < 4; ++r) {          // two-term bf16 split of mh
                float m = c[r] + bcv;
                bf16 hb = f2b(m);
                R4[(row0 + r) * KSTR + col] = hb;
                R1[(row0 + r) * KSTR + col] = f2b(m - b2f(hb));
            }
        }
    }

    // ---------------- Phase F: score2 -> tanh/mask -> softmax -> store -----
    __syncthreads();
    stage_m(encB, N_, R2, tid);
    __syncthreads();
    if (wave < 7) {
        short8 ahi[4], alo[4];
        #pragma unroll
        for (int s = 0; s < 4; ++s) {
            ahi[s] = *(const short8*)(R4 + (wave * 16 + lr) * KSTR + s * 32 + lk);
            alo[s] = *(const short8*)(R1 + (wave * 16 + lr) * KSTR + s * 32 + lk);
        }
        float sc[7][4];
        #pragma unroll
        for (int nt = 0; nt < 7; ++nt) {
            float4v cc = {0.f, 0.f, 0.f, 0.f};
            #pragma unroll
            for (int s = 0; s < 4; ++s) {
                short8 bb = *(const short8*)(R2 + (nt * 16 + lr) * KSTR + s * 32 + lk);
                cc = __builtin_amdgcn_mfma_f32_16x16x32_bf16(ahi[s], bb, cc, 0, 0, 0);
                cc = __builtin_amdgcn_mfma_f32_16x16x32_bf16(alo[s], bb, cc, 0, 0, 0);
            }
            #pragma unroll
            for (int r = 0; r < 4; ++r) {
                float x = cc[r] * 0.08838834764831845f;              // 1/sqrt(128)
                float t = 1.0f - 2.0f / (__expf(2.0f * x) + 1.0f);   // safe tanh
                sc[nt][r] = 10.0f * t + msk[nt][r];                  // n>=101 -> -3e38
            }
        }
        #pragma unroll
        for (int r = 0; r < 4; ++r) {
            float m = sc[0][r];
            #pragma unroll
            for (int nt = 1; nt < 7; ++nt) m = fmaxf(m, sc[nt][r]);
            #pragma unroll
            for (int d = 1; d < 16; d <<= 1) m = fmaxf(m, __shfl_xor(m, d));
            float su = 0.f;
            #pragma unroll
            for (int nt = 0; nt < 7; ++nt) {
                float e = __expf(sc[nt][r] - m); sc[nt][r] = e; su += e;
            }
            #pragma unroll
            for (int d = 1; d < 16; d <<= 1) su += __shfl_xor(su, d);
            float inv = 1.0f / su;
            int p = wave * 16 + (lq << 2) + r;
            if (p < P_) {
                #pragma unroll
                for (int nt = 0; nt < 7; ++nt) {
                    int n = nt * 16 + lr;
                    if (n < N_) outB[(size_t)p * N_ + n] = sc[nt][r] * inv;
                }
            }
        }
    }
}

extern "C" void kernel_launch(void* const* d_in, const int* in_sizes, int n_in,
                              void* d_out, int out_size, void* d_ws, size_t ws_size,
                              hipStream_t stream) {
    const float* eln   = (const float*)d_in[0];
    const float* load_ = (const float*)d_in[1];
    const float* time_ = (const float*)d_in[2];
    const float* len_  = (const float*)d_in[3];
    const float* open_ = (const float*)d_in[4];
    const float* mask_ = (const float*)d_in[5];
    const float* enc_  = (const float*)d_in[6];
    const float* Wq    = (const float*)d_in[7];
    const float* Wk    = (const float*)d_in[8];
    const float* Wv    = (const float*)d_in[9];
    const float* Wc    = (const float*)d_in[10];
    const float* bc    = (const float*)d_in[11];
    float* out = (float*)d_out;

    vrp_kernel<<<dim3(B_), dim3(512), 0, stream>>>(
        eln, load_, time_, len_, open_, mask_, enc_, Wq, Wk, Wv, Wc, bc, out);
}

// Round 6
// 316.170 us; speedup vs baseline: 8.7166x; 1.1402x over previous
//
#include <hip/hip_runtime.h>
#include <stdint.h>

#define B_    1024
#define P_    100
#define N_    101
#define EMB_  128
#define H_    8
#define DK_   16

#define ROWS  112          // 7 m-tiles of 16 (covers P=100 / N=101)
#define KSTR  136          // LDS row stride in bf16 elems (272 B -> 2-way-free banks)

typedef uint16_t bf16;
typedef __attribute__((ext_vector_type(8))) short short8;
typedef __attribute__((ext_vector_type(4))) float float4v;

__device__ __forceinline__ float b2f(bf16 u) {
    union { uint32_t i; float f; } c; c.i = ((uint32_t)u) << 16; return c.f;
}
__device__ __forceinline__ bf16 f2b(float f) {
    union { float f; uint32_t i; } c; c.f = f;
    uint32_t r = (c.i + 0x7fffu + ((c.i >> 16) & 1u)) >> 16;   // RNE
    return (bf16)r;
}
__device__ __forceinline__ uint32_t pk2(float a, float b) {
    return (uint32_t)f2b(a) | ((uint32_t)f2b(b) << 16);
}

// stage f32 [nrows][128] row-major -> bf16 LDS [ROWS][KSTR], zero pad rows
__device__ __forceinline__ void stage_m(const float* __restrict__ src, int nrows,
                                        bf16* __restrict__ dst, int tid) {
    for (int i = tid; i < ROWS * 32; i += 512) {
        int r = i >> 5, c = (i & 31) << 2;
        uint32_t p0 = 0, p1 = 0;
        if (r < nrows) {
            float4 v = *(const float4*)(src + (size_t)r * EMB_ + c);
            p0 = pk2(v.x, v.y); p1 = pk2(v.z, v.w);
        }
        uint32_t* d = (uint32_t*)(dst + r * KSTR + c);
        d[0] = p0; d[1] = p1;
    }
}

// ---- prep: W f32 [k][o] -> ws bf16 W^T [o][k], order: Wk, Wv, Wq, Wc ------
__global__ __launch_bounds__(256)
void prep_wT(const float* __restrict__ Wq, const float* __restrict__ Wk,
             const float* __restrict__ Wv, const float* __restrict__ Wc,
             bf16* __restrict__ ws) {
    int idx = blockIdx.x * 256 + threadIdx.x;      // 65536 threads
    int w = idx >> 14, rem = idx & 16383;
    int k = rem >> 7, o = rem & 127;               // o innermost: coalesced read
    const float* W = (w == 0) ? Wk : (w == 1) ? Wv : (w == 2) ? Wq : Wc;
    ws[((size_t)w << 14) + o * 128 + k] = f2b(W[(size_t)k * 128 + o]);
}

__global__ __launch_bounds__(512, 2)
void vrp_kernel(const float* __restrict__ eln,
                const float* __restrict__ load_,
                const float* __restrict__ time_,
                const float* __restrict__ len_,
                const float* __restrict__ open_,
                const float* __restrict__ mask_,
                const float* __restrict__ enc_,
                const float* __restrict__ Wq,
                const float* __restrict__ bc,
                const bf16* __restrict__ wsWT,
                float* __restrict__ out)
{
    const int b    = blockIdx.x;
    const int tid  = threadIdx.x;
    const int wave = tid >> 6;
    const int lane = tid & 63;
    const int lr = lane & 15, lq = lane >> 4, lk = lq << 3;

    // Overlays: R1 enc/P/mh-lo ; R2 K/enc2 ; R3 V^T ; R4 Q/mh-hi ; R5 cat/O
    __shared__ bf16 smem[78336];
    __shared__ float sS4[ROWS * 4];
    __shared__ float sWq4[4 * EMB_];
    bf16* const R1 = smem;
    bf16* const R2 = smem + 15232;
    bf16* const R3 = smem + 30464;
    bf16* const R4 = smem + 47872;
    bf16* const R5 = smem + 63104;

    const bf16* WkT = wsWT;
    const bf16* WvT = wsWT + 16384;
    const bf16* WqT = wsWT + 32768;
    const bf16* WcT = wsWT + 49152;

    const float* encB  = enc_  + (size_t)b * N_ * EMB_;
    const float* elnB  = eln   + (size_t)b * P_ * EMB_;
    const float* maskB = mask_ + (size_t)b * P_ * N_;
    float*       outB  = out   + (size_t)b * P_ * N_;

    // ---------------- Phase A: stage enc->R1, cat->R5, extras --------------
    stage_m(encB, N_, R1, tid);
    stage_m(elnB, P_, R5, tid);
    {   // zero sVt[d][112..127]  (PV kstep 3 reads n=96..127)
        int d = tid >> 2, c = 112 + ((tid & 3) << 2);
        uint32_t* z = (uint32_t*)(R3 + d * KSTR + c);
        z[0] = 0; z[1] = 0;
    }
    if (tid < ROWS * 4) {
        int r = tid >> 2, j = tid & 3;
        float v = 0.f;
        if (r < P_) {
            const float* s4 = (j == 0) ? load_ : (j == 1) ? time_
                             : (j == 2) ? len_ : open_;
            v = s4[(size_t)b * P_ + r];
        }
        sS4[r * 4 + j] = v;
    }
    {
        int j = tid >> 7, c = tid & 127;
        sWq4[j * EMB_ + c] = Wq[(size_t)(EMB_ + j) * EMB_ + c];
    }
    __syncthreads();

    // ------- Phase B+C: K->R2, V^T->R3, Q'->R4 (one barrier window) --------
    {
        const int col = 16 * wave + lr;           // my out column
        short8 bk[4], bv[4], bq[4];
        {
            const bf16* rk = WkT + (size_t)col * 128 + lk;
            const bf16* rv = WvT + (size_t)col * 128 + lk;
            const bf16* rq = WqT + (size_t)col * 128 + lk;
            #pragma unroll
            for (int s = 0; s < 4; ++s) {
                bk[s] = *(const short8*)(rk + s * 32);
                bv[s] = *(const short8*)(rv + s * 32);
                bq[s] = *(const short8*)(rq + s * 32);
            }
        }
        #pragma unroll
        for (int mt = 0; mt < 7; ++mt) {          // K and V share enc A-frags
            short8 a[4];
            #pragma unroll
            for (int s = 0; s < 4; ++s)
                a[s] = *(const short8*)(R1 + (mt * 16 + lr) * KSTR + s * 32 + lk);
            float4v ck = {0.f, 0.f, 0.f, 0.f}, cv = {0.f, 0.f, 0.f, 0.f};
            #pragma unroll
            for (int s = 0; s < 4; ++s) {
                ck = __builtin_amdgcn_mfma_f32_16x16x32_bf16(a[s], bk[s], ck, 0, 0, 0);
                cv = __builtin_amdgcn_mfma_f32_16x16x32_bf16(a[s], bv[s], cv, 0, 0, 0);
            }
            int n0 = mt * 16 + (lq << 2);
            #pragma unroll
            for (int r = 0; r < 4; ++r)
                R2[(n0 + r) * KSTR + col] = f2b(ck[r]);       // K [n][col]
            uint32_t* d = (uint32_t*)(R3 + col * KSTR + n0);  // V^T [d][n]
            d[0] = pk2(cv[0], cv[1]);
            d[1] = pk2(cv[2], cv[3]);
        }
        #pragma unroll
        for (int mt = 0; mt < 7; ++mt) {          // Q' = 0.25*(cat@Wq)
            short8 a[4];
            #pragma unroll
            for (int s = 0; s < 4; ++s)
                a[s] = *(const short8*)(R5 + (mt * 16 + lr) * KSTR + s * 32 + lk);
            float4v c = {0.f, 0.f, 0.f, 0.f};
            #pragma unroll
            for (int s = 0; s < 4; ++s)
                c = __builtin_amdgcn_mfma_f32_16x16x32_bf16(a[s], bq[s], c, 0, 0, 0);
            int row0 = mt * 16 + (lq << 2);
            float w0 = sWq4[col], w1 = sWq4[EMB_ + col];
            float w2 = sWq4[2 * EMB_ + col], w3 = sWq4[3 * EMB_ + col];
            #pragma unroll
            for (int r = 0; r < 4; ++r) {
                const float* s4 = sS4 + (row0 + r) * 4;
                float acc = c[r] + s4[0] * w0 + s4[1] * w1 + s4[2] * w2 + s4[3] * w3;
                R4[(row0 + r) * KSTR + col] = f2b(acc * 0.25f);
            }
        }
    }
    __syncthreads();

    // ---------------- Phase D: attention (no barriers inside) --------------
    float msk[7][4];
    if (wave < 7) {
        {   // zero sP pad cols 112..127 of my p-tile
            uint32_t* z = (uint32_t*)(R1 + (wave * 16 + lr) * KSTR + 112 + (lq << 2));
            z[0] = 0; z[1] = 0;
        }
        #pragma unroll
        for (int nt = 0; nt < 7; ++nt) {
            int n = nt * 16 + lr;
            #pragma unroll
            for (int r = 0; r < 4; ++r) {
                int p = wave * 16 + (lq << 2) + r;
                float v;
                if (n >= N_) v = -3.0e38f;
                else if (p < P_) v = maskB[(size_t)p * N_ + n];
                else v = 0.f;
                msk[nt][r] = v;
            }
        }
        for (int h = 0; h < H_; ++h) {
            int k0 = (h >> 1) << 5;                 // 32-wide k-window
            float sc[7][4];
            short8 a = *(const short8*)(R4 + (wave * 16 + lr) * KSTR + k0 + lk);
            #pragma unroll
            for (int nt = 0; nt < 7; ++nt) {
                short8 bb = *(const short8*)(R2 + (nt * 16 + lr) * KSTR + k0 + lk);
                if ((lq >> 1) != (h & 1)) bb = (short8){0,0,0,0,0,0,0,0};
                float4v cc = {0.f, 0.f, 0.f, 0.f};
                cc = __builtin_amdgcn_mfma_f32_16x16x32_bf16(a, bb, cc, 0, 0, 0);
                #pragma unroll
                for (int r = 0; r < 4; ++r) sc[nt][r] = cc[r] + msk[nt][r];
            }
            #pragma unroll
            for (int r = 0; r < 4; ++r) {           // in-register row softmax
                float m = sc[0][r];
                #pragma unroll
                for (int nt = 1; nt < 7; ++nt) m = fmaxf(m, sc[nt][r]);
                #pragma unroll
                for (int d = 1; d < 16; d <<= 1) m = fmaxf(m, __shfl_xor(m, d));
                float su = 0.f;
                #pragma unroll
                for (int nt = 0; nt < 7; ++nt) {
                    float e = __expf(sc[nt][r] - m); sc[nt][r] = e; su += e;
                }
                #pragma unroll
                for (int d = 1; d < 16; d <<= 1) su += __shfl_xor(su, d);
                float inv = 1.0f / su;
                #pragma unroll
                for (int nt = 0; nt < 7; ++nt)      // P -> LDS in A-layout
                    R1[(wave * 16 + (lq << 2) + r) * KSTR + nt * 16 + lr] =
                        f2b(sc[nt][r] * inv);
            }
            float4v o = {0.f, 0.f, 0.f, 0.f};       // PV
            #pragma unroll
            for (int ks = 0; ks < 128; ks += 32) {
                short8 a2 = *(const short8*)(R1 + (wave * 16 + lr) * KSTR + ks + lk);
                short8 b2 = *(const short8*)(R3 + (h * 16 + lr) * KSTR + ks + lk);
                o = __builtin_amdgcn_mfma_f32_16x16x32_bf16(a2, b2, o, 0, 0, 0);
            }
            #pragma unroll
            for (int r = 0; r < 4; ++r)             // O -> R5 (cat dead)
                R5[(wave * 16 + (lq << 2) + r) * KSTR + h * 16 + lr] = f2b(o[r]);
        }
    }
    __syncthreads();

    // ---- Phase E: mh = O@Wc + bc -> hi(R4)+lo(R1); stage enc2 -> R2 -------
    stage_m(encB, N_, R2, tid);                     // K dead
    {
        const int col = 16 * wave + lr;
        short8 bw[4];
        {
            const bf16* rc = WcT + (size_t)col * 128 + lk;
            #pragma unroll
            for (int s = 0; s < 4; ++s) bw[s] = *(const short8*)(rc + s * 32);
        }
        float bcv = bc[col];
        #pragma unroll
        for (int mt = 0; mt < 7; ++mt) {
            short8 a[4];
            #pragma unroll
            for (int s = 0; s < 4; ++s)
                a[s] = *(const short8*)(R5 + (mt * 16 + lr) * KSTR + s * 32 + lk);
            float4v c = {0.f, 0.f, 0.f, 0.f};
            #pragma unroll
            for (int s = 0; s < 4; ++s)
                c = __builtin_amdgcn_mfma_f32_16x16x32_bf16(a[s], bw[s], c, 0, 0, 0);
            int row0 = mt * 16 + (lq << 2);
            #pragma unroll
            for (int r = 0; r < 4; ++r) {           // two-term bf16 split of mh
                float m = c[r] + bcv;
                bf16 hb = f2b(m);
                R4[(row0 + r) * KSTR + col] = hb;
                R1[(row0 + r) * KSTR + col] = f2b(m - b2f(hb));
            }
        }
    }
    __syncthreads();

    // ---------------- Phase F: score2 -> tanh/mask -> softmax -> store -----
    if (wave < 7) {
        short8 ahi[4], alo[4];
        #pragma unroll
        for (int s = 0; s < 4; ++s) {
            ahi[s] = *(const short8*)(R4 + (wave * 16 + lr) * KSTR + s * 32 + lk);
            alo[s] = *(const short8*)(R1 + (wave * 16 + lr) * KSTR + s * 32 + lk);
        }
        float sc[7][4];
        #pragma unroll
        for (int nt = 0; nt < 7; ++nt) {
            float4v cc = {0.f, 0.f, 0.f, 0.f};
            #pragma unroll
            for (int s = 0; s < 4; ++s) {
                short8 bb = *(const short8*)(R2 + (nt * 16 + lr) * KSTR + s * 32 + lk);
                cc = __builtin_amdgcn_mfma_f32_16x16x32_bf16(ahi[s], bb, cc, 0, 0, 0);
                cc = __builtin_amdgcn_mfma_f32_16x16x32_bf16(alo[s], bb, cc, 0, 0, 0);
            }
            #pragma unroll
            for (int r = 0; r < 4; ++r) {
                float x = cc[r] * 0.08838834764831845f;              // 1/sqrt(128)
                float t = 1.0f - 2.0f / (__expf(2.0f * x) + 1.0f);   // safe tanh
                sc[nt][r] = 10.0f * t + msk[nt][r];
            }
        }
        #pragma unroll
        for (int r = 0; r < 4; ++r) {
            float m = sc[0][r];
            #pragma unroll
            for (int nt = 1; nt < 7; ++nt) m = fmaxf(m, sc[nt][r]);
            #pragma unroll
            for (int d = 1; d < 16; d <<= 1) m = fmaxf(m, __shfl_xor(m, d));
            float su = 0.f;
            #pragma unroll
            for (int nt = 0; nt < 7; ++nt) {
                float e = __expf(sc[nt][r] - m); sc[nt][r] = e; su += e;
            }
            #pragma unroll
            for (int d = 1; d < 16; d <<= 1) su += __shfl_xor(su, d);
            float inv = 1.0f / su;
            int p = wave * 16 + (lq << 2) + r;
            if (p < P_) {
                #pragma unroll
                for (int nt = 0; nt < 7; ++nt) {
                    int n = nt * 16 + lr;
                    if (n < N_) outB[(size_t)p * N_ + n] = sc[nt][r] * inv;
                }
            }
        }
    }
}

extern "C" void kernel_launch(void* const* d_in, const int* in_sizes, int n_in,
                              void* d_out, int out_size, void* d_ws, size_t ws_size,
                              hipStream_t stream) {
    const float* eln   = (const float*)d_in[0];
    const float* load_ = (const float*)d_in[1];
    const float* time_ = (const float*)d_in[2];
    const float* len_  = (const float*)d_in[3];
    const float* open_ = (const float*)d_in[4];
    const float* mask_ = (const float*)d_in[5];
    const float* enc_  = (const float*)d_in[6];
    const float* Wq    = (const float*)d_in[7];
    const float* Wk    = (const float*)d_in[8];
    const float* Wv    = (const float*)d_in[9];
    const float* Wc    = (const float*)d_in[10];
    const float* bc    = (const float*)d_in[11];
    float* out = (float*)d_out;
    bf16* wsWT = (bf16*)d_ws;                      // 4*16384*2 = 131072 B

    prep_wT<<<dim3(256), dim3(256), 0, stream>>>(Wq, Wk, Wv, Wc, wsWT);
    vrp_kernel<<<dim3(B_), dim3(512), 0, stream>>>(
        eln, load_, time_, len_, open_, mask_, enc_, Wq, bc, wsWT, out);
}

// Round 7
// 303.797 us; speedup vs baseline: 9.0716x; 1.0407x over previous
//
#include <hip/hip_runtime.h>
#include <stdint.h>

#define B_    1024
#define P_    100
#define N_    101
#define EMB_  128
#define H_    8
#define DK_   16

#define ROWS  112          // 7 m-tiles of 16 (covers P=100 / N=101)
#define KSTR  136          // LDS row stride in bf16 elems

typedef uint16_t bf16;
typedef __attribute__((ext_vector_type(8))) short short8;
typedef __attribute__((ext_vector_type(4))) float float4v;

__device__ __forceinline__ float b2f(bf16 u) {
    union { uint32_t i; float f; } c; c.i = ((uint32_t)u) << 16; return c.f;
}
__device__ __forceinline__ bf16 f2b(float f) {
    union { float f; uint32_t i; } c; c.f = f;
    uint32_t r = (c.i + 0x7fffu + ((c.i >> 16) & 1u)) >> 16;   // RNE
    return (bf16)r;
}
__device__ __forceinline__ uint32_t pk2(float a, float b) {
    return (uint32_t)f2b(a) | ((uint32_t)f2b(b) << 16);
}

// stage f32 [nrows][128] row-major -> bf16 LDS [ROWS][KSTR], zero pad rows
__device__ __forceinline__ void stage_m(const float* __restrict__ src, int nrows,
                                        bf16* __restrict__ dst, int tid) {
    for (int i = tid; i < ROWS * 32; i += 1024) {
        int r = i >> 5, c = (i & 31) << 2;
        uint32_t p0 = 0, p1 = 0;
        if (r < nrows) {
            float4 v = *(const float4*)(src + (size_t)r * EMB_ + c);
            p0 = pk2(v.x, v.y); p1 = pk2(v.z, v.w);
        }
        uint32_t* d = (uint32_t*)(dst + r * KSTR + c);
        d[0] = p0; d[1] = p1;
    }
}

// ---- prep: W f32 [k][o] -> ws bf16 W^T [o][k], order: Wk, Wv, Wq, Wc ------
__global__ __launch_bounds__(256)
void prep_wT(const float* __restrict__ Wq, const float* __restrict__ Wk,
             const float* __restrict__ Wv, const float* __restrict__ Wc,
             bf16* __restrict__ ws) {
    int idx = blockIdx.x * 256 + threadIdx.x;      // 65536 threads
    int w = idx >> 14, rem = idx & 16383;
    int k = rem >> 7, o = rem & 127;               // o innermost: coalesced read
    const float* W = (w == 0) ? Wk : (w == 1) ? Wv : (w == 2) ? Wq : Wc;
    ws[((size_t)w << 14) + o * 128 + k] = f2b(W[(size_t)k * 128 + o]);
}

__global__ __launch_bounds__(1024, 4)
void vrp_kernel(const float* __restrict__ eln,
                const float* __restrict__ load_,
                const float* __restrict__ time_,
                const float* __restrict__ len_,
                const float* __restrict__ open_,
                const float* __restrict__ mask_,
                const float* __restrict__ enc_,
                const float* __restrict__ Wq,
                const float* __restrict__ bc,
                const bf16* __restrict__ wsWT,
                float* __restrict__ out)
{
    const int b    = blockIdx.x;
    const int tid  = threadIdx.x;
    const int wave = tid >> 6;
    const int lane = tid & 63;
    const int lr = lane & 15, lq = lane >> 4, lk = lq << 3;

    // Overlays: R1 enc/P0/mh-hi ; R2 K/enc2 ; R3 V^T ; R4 Q/O ; R5 cat/P1/mh-lo
    __shared__ bf16 smem[78336];
    __shared__ float sS4[ROWS * 4];
    __shared__ float sWq4[4 * EMB_];
    bf16* const R1 = smem;
    bf16* const R2 = smem + 15232;
    bf16* const R3 = smem + 30464;
    bf16* const R4 = smem + 47872;
    bf16* const R5 = smem + 63104;

    const bf16* WkT = wsWT;
    const bf16* WvT = wsWT + 16384;
    const bf16* WqT = wsWT + 32768;
    const bf16* WcT = wsWT + 49152;

    const float* encB  = enc_  + (size_t)b * N_ * EMB_;
    const float* elnB  = eln   + (size_t)b * P_ * EMB_;
    const float* maskB = mask_ + (size_t)b * P_ * N_;
    float*       outB  = out   + (size_t)b * P_ * N_;

    // ---------------- Phase A: stage enc->R1, cat->R5, extras --------------
    stage_m(encB, N_, R1, tid);
    stage_m(elnB, P_, R5, tid);
    if (tid < 512) {   // zero sVt[d][112..127]
        int d = tid >> 2, c = 112 + ((tid & 3) << 2);
        uint32_t* z = (uint32_t*)(R3 + d * KSTR + c);
        z[0] = 0; z[1] = 0;
    }
    if (tid < ROWS * 4) {
        int r = tid >> 2, j = tid & 3;
        float v = 0.f;
        if (r < P_) {
            const float* s4 = (j == 0) ? load_ : (j == 1) ? time_
                             : (j == 2) ? len_ : open_;
            v = s4[(size_t)b * P_ + r];
        }
        sS4[r * 4 + j] = v;
    }
    if (tid < 512) {
        int j = tid >> 7, c = tid & 127;
        sWq4[j * EMB_ + c] = Wq[(size_t)(EMB_ + j) * EMB_ + c];
    }
    __syncthreads();

    // ------- Phase B+C: K->R2, V^T->R3, Q'->R4 (one barrier window) --------
    // 16 waves = 8 col-tiles x 2 m-tile halves
    {
        const int col = 16 * (wave & 7) + lr;
        const int mt0 = (wave >> 3) ? 4 : 0;
        const int mt1 = (wave >> 3) ? 7 : 4;
        short8 bk[4], bv[4], bq[4];
        {
            const bf16* rk = WkT + (size_t)col * 128 + lk;
            const bf16* rv = WvT + (size_t)col * 128 + lk;
            const bf16* rq = WqT + (size_t)col * 128 + lk;
            #pragma unroll
            for (int s = 0; s < 4; ++s) {
                bk[s] = *(const short8*)(rk + s * 32);
                bv[s] = *(const short8*)(rv + s * 32);
                bq[s] = *(const short8*)(rq + s * 32);
            }
        }
        float w0 = sWq4[col], w1 = sWq4[EMB_ + col];
        float w2 = sWq4[2 * EMB_ + col], w3 = sWq4[3 * EMB_ + col];
        for (int mt = mt0; mt < mt1; ++mt) {
            short8 a[4];
            #pragma unroll
            for (int s = 0; s < 4; ++s)
                a[s] = *(const short8*)(R1 + (mt * 16 + lr) * KSTR + s * 32 + lk);
            float4v ck = {0.f, 0.f, 0.f, 0.f}, cv = {0.f, 0.f, 0.f, 0.f};
            #pragma unroll
            for (int s = 0; s < 4; ++s) {
                ck = __builtin_amdgcn_mfma_f32_16x16x32_bf16(a[s], bk[s], ck, 0, 0, 0);
                cv = __builtin_amdgcn_mfma_f32_16x16x32_bf16(a[s], bv[s], cv, 0, 0, 0);
            }
            int n0 = mt * 16 + (lq << 2);
            #pragma unroll
            for (int r = 0; r < 4; ++r)
                R2[(n0 + r) * KSTR + col] = f2b(ck[r]);       // K [n][col]
            uint32_t* d = (uint32_t*)(R3 + col * KSTR + n0);  // V^T [d][n]
            d[0] = pk2(cv[0], cv[1]);
            d[1] = pk2(cv[2], cv[3]);
            // Q' = 0.25*(cat@Wq) for same mt
            short8 aq[4];
            #pragma unroll
            for (int s = 0; s < 4; ++s)
                aq[s] = *(const short8*)(R5 + (mt * 16 + lr) * KSTR + s * 32 + lk);
            float4v cq = {0.f, 0.f, 0.f, 0.f};
            #pragma unroll
            for (int s = 0; s < 4; ++s)
                cq = __builtin_amdgcn_mfma_f32_16x16x32_bf16(aq[s], bq[s], cq, 0, 0, 0);
            int row0 = mt * 16 + (lq << 2);
            #pragma unroll
            for (int r = 0; r < 4; ++r) {
                const float* s4 = sS4 + (row0 + r) * 4;
                float acc = cq[r] + s4[0] * w0 + s4[1] * w1 + s4[2] * w2 + s4[3] * w3;
                R4[(row0 + r) * KSTR + col] = f2b(acc * 0.25f);
            }
        }
    }
    __syncthreads();

    // -------- Phase D: attention; 14 waves = 7 p-tiles x 2 head-groups -----
    const int hg = (wave >= 7) ? 1 : 0;
    const int pt = wave - hg * 7;
    float msk[7][4];
    float4v o4[4];
    if (wave < 14) {
        bf16* Pbuf = hg ? R5 : R1;                  // enc / cat both dead
        {   // zero pad cols 112..127 of my p-tile rows
            uint32_t* z = (uint32_t*)(Pbuf + (pt * 16 + lr) * KSTR + 112 + (lq << 2));
            z[0] = 0; z[1] = 0;
        }
        #pragma unroll
        for (int nt = 0; nt < 7; ++nt) {
            int n = nt * 16 + lr;
            #pragma unroll
            for (int r = 0; r < 4; ++r) {
                int p = pt * 16 + (lq << 2) + r;
                float v;
                if (n >= N_) v = -3.0e38f;
                else if (p < P_) v = maskB[(size_t)p * N_ + n];
                else v = 0.f;
                msk[nt][r] = v;
            }
        }
        #pragma unroll
        for (int hh = 0; hh < 4; ++hh) {
            int h  = hg * 4 + hh;
            int k0 = (h >> 1) << 5;                 // 32-wide k-window
            float sc[7][4];
            short8 a = *(const short8*)(R4 + (pt * 16 + lr) * KSTR + k0 + lk);
            #pragma unroll
            for (int nt = 0; nt < 7; ++nt) {
                short8 bb = *(const short8*)(R2 + (nt * 16 + lr) * KSTR + k0 + lk);
                if ((lq >> 1) != (h & 1)) bb = (short8){0,0,0,0,0,0,0,0};
                float4v cc = {0.f, 0.f, 0.f, 0.f};
                cc = __builtin_amdgcn_mfma_f32_16x16x32_bf16(a, bb, cc, 0, 0, 0);
                #pragma unroll
                for (int r = 0; r < 4; ++r) sc[nt][r] = cc[r] + msk[nt][r];
            }
            #pragma unroll
            for (int r = 0; r < 4; ++r) {           // in-register row softmax
                float m = sc[0][r];
                #pragma unroll
                for (int nt = 1; nt < 7; ++nt) m = fmaxf(m, sc[nt][r]);
                #pragma unroll
                for (int d = 1; d < 16; d <<= 1) m = fmaxf(m, __shfl_xor(m, d));
                float su = 0.f;
                #pragma unroll
                for (int nt = 0; nt < 7; ++nt) {
                    float e = __expf(sc[nt][r] - m); sc[nt][r] = e; su += e;
                }
                #pragma unroll
                for (int d = 1; d < 16; d <<= 1) su += __shfl_xor(su, d);
                float inv = 1.0f / su;
                #pragma unroll
                for (int nt = 0; nt < 7; ++nt)      // P -> LDS in A-layout
                    Pbuf[(pt * 16 + (lq << 2) + r) * KSTR + nt * 16 + lr] =
                        f2b(sc[nt][r] * inv);
            }
            float4v o = {0.f, 0.f, 0.f, 0.f};       // PV -> registers
            #pragma unroll
            for (int ks = 0; ks < 128; ks += 32) {
                short8 a2 = *(const short8*)(Pbuf + (pt * 16 + lr) * KSTR + ks + lk);
                short8 b2 = *(const short8*)(R3 + (h * 16 + lr) * KSTR + ks + lk);
                o = __builtin_amdgcn_mfma_f32_16x16x32_bf16(a2, b2, o, 0, 0, 0);
            }
            o4[hh] = o;
        }
    }
    __syncthreads();                                // all Q reads done

    // ---- O regs -> R4 (over Q); stage enc2 -> R2 (over K) -----------------
    if (wave < 14) {
        #pragma unroll
        for (int hh = 0; hh < 4; ++hh) {
            int h = hg * 4 + hh;
            #pragma unroll
            for (int r = 0; r < 4; ++r)
                R4[(pt * 16 + (lq << 2) + r) * KSTR + h * 16 + lr] = f2b(o4[hh][r]);
        }
    }
    stage_m(encB, N_, R2, tid);
    __syncthreads();

    // ---- Phase E: mh = O@Wc + bc -> hi(R1)+lo(R5)  (P buffers dead) -------
    {
        const int col = 16 * (wave & 7) + lr;
        const int mt0 = (wave >> 3) ? 4 : 0;
        const int mt1 = (wave >> 3) ? 7 : 4;
        short8 bw[4];
        {
            const bf16* rc = WcT + (size_t)col * 128 + lk;
            #pragma unroll
            for (int s = 0; s < 4; ++s) bw[s] = *(const short8*)(rc + s * 32);
        }
        float bcv = bc[col];
        for (int mt = mt0; mt < mt1; ++mt) {
            short8 a[4];
            #pragma unroll
            for (int s = 0; s < 4; ++s)
                a[s] = *(const short8*)(R4 + (mt * 16 + lr) * KSTR + s * 32 + lk);
            float4v c = {0.f, 0.f, 0.f, 0.f};
            #pragma unroll
            for (int s = 0; s < 4; ++s)
                c = __builtin_amdgcn_mfma_f32_16x16x32_bf16(a[s], bw[s], c, 0, 0, 0);
            int row0 = mt * 16 + (lq << 2);
            #pragma unroll
            for (int r = 0; r < 4; ++r) {           // two-term bf16 split of mh
                float m = c[r] + bcv;
                bf16 hb = f2b(m);
                R1[(row0 + r) * KSTR + col] = hb;
                R5[(row0 + r) * KSTR + col] = f2b(m - b2f(hb));
            }
        }
    }
    __syncthreads();

    // ---------------- Phase F: score2 -> tanh/mask -> softmax -> store -----
    if (wave < 7) {
        short8 ahi[4], alo[4];
        #pragma unroll
        for (int s = 0; s < 4; ++s) {
            ahi[s] = *(const short8*)(R1 + (pt * 16 + lr) * KSTR + s * 32 + lk);
            alo[s] = *(const short8*)(R5 + (pt * 16 + lr) * KSTR + s * 32 + lk);
        }
        float sc[7][4];
        #pragma unroll
        for (int nt = 0; nt < 7; ++nt) {
            float4v cc = {0.f, 0.f, 0.f, 0.f};
            #pragma unroll
            for (int s = 0; s < 4; ++s) {
                short8 bb = *(const short8*)(R2 + (nt * 16 + lr) * KSTR + s * 32 + lk);
                cc = __builtin_amdgcn_mfma_f32_16x16x32_bf16(ahi[s], bb, cc, 0, 0, 0);
                cc = __builtin_amdgcn_mfma_f32_16x16x32_bf16(alo[s], bb, cc, 0, 0, 0);
            }
            #pragma unroll
            for (int r = 0; r < 4; ++r) {
                float x = cc[r] * 0.08838834764831845f;              // 1/sqrt(128)
                float t = 1.0f - 2.0f / (__expf(2.0f * x) + 1.0f);   // safe tanh
                sc[nt][r] = 10.0f * t + msk[nt][r];
            }
        }
        #pragma unroll
        for (int r = 0; r < 4; ++r) {
            float m = sc[0][r];
            #pragma unroll
            for (int nt = 1; nt < 7; ++nt) m = fmaxf(m, sc[nt][r]);
            #pragma unroll
            for (int d = 1; d < 16; d <<= 1) m = fmaxf(m, __shfl_xor(m, d));
            float su = 0.f;
            #pragma unroll
            for (int nt = 0; nt < 7; ++nt) {
                float e = __expf(sc[nt][r] - m); sc[nt][r] = e; su += e;
            }
            #pragma unroll
            for (int d = 1; d < 16; d <<= 1) su += __shfl_xor(su, d);
            float inv = 1.0f / su;
            int p = pt * 16 + (lq << 2) + r;
            if (p < P_) {
                #pragma unroll
                for (int nt = 0; nt < 7; ++nt) {
                    int n = nt * 16 + lr;
                    if (n < N_) outB[(size_t)p * N_ + n] = sc[nt][r] * inv;
                }
            }
        }
    }
}

extern "C" void kernel_launch(void* const* d_in, const int* in_sizes, int n_in,
                              void* d_out, int out_size, void* d_ws, size_t ws_size,
                              hipStream_t stream) {
    const float* eln   = (const float*)d_in[0];
    const float* load_ = (const float*)d_in[1];
    const float* time_ = (const float*)d_in[2];
    const float* len_  = (const float*)d_in[3];
    const float* open_ = (const float*)d_in[4];
    const float* mask_ = (const float*)d_in[5];
    const float* enc_  = (const float*)d_in[6];
    const float* Wq    = (const float*)d_in[7];
    const float* Wk    = (const float*)d_in[8];
    const float* Wv    = (const float*)d_in[9];
    const float* Wc    = (const float*)d_in[10];
    const float* bc    = (const float*)d_in[11];
    float* out = (float*)d_out;
    bf16* wsWT = (bf16*)d_ws;                      // 4*16384*2 = 131072 B

    prep_wT<<<dim3(256), dim3(256), 0, stream>>>(Wq, Wk, Wv, Wc, wsWT);
    vrp_kernel<<<dim3(B_), dim3(1024), 0, stream>>>(
        eln, load_, time_, len_, open_, mask_, enc_, Wq, bc, wsWT, out);
}